// Round 10
// baseline (150.641 us; speedup 1.0000x reference)
//
#include <hip/hip_runtime.h>

typedef unsigned short u16;
typedef unsigned int u32;

typedef __attribute__((ext_vector_type(8))) __bf16 bf16x8;
typedef __attribute__((ext_vector_type(4))) float floatx4;

#define B_ 2
#define L_ 2048
#define H_ 16
#define E_ 64
#define QK_ELEMS (B_ * H_ * L_ * E_) /* 4194304 elements */
#define WS_OFF 128                   /* staged tensors at +128 elems into ws */

static __device__ __forceinline__ float bf2f(u16 v) {
  u32 u = ((u32)v) << 16;
  return __builtin_bit_cast(float, u);
}
static __device__ __forceinline__ u16 f2bf(float x) {
  u32 u = __builtin_bit_cast(u32, x);
  u32 r = (u + 0x7FFFu + ((u >> 16) & 1u)) >> 16;
  return (u16)r;
}

// packed f32->bf16 (RNE): dst[15:0]=bf16(lo), dst[31:16]=bf16(hi)
static __device__ __forceinline__ u32 cvtpk_bf16(float lo, float hi) {
  u32 r;
  asm("v_cvt_pk_bf16_f32 %0, %1, %2" : "=v"(r) : "v"(lo), "v"(hi));
  return r;
}

static __device__ __forceinline__ float exp2_fast(float x) {
  float r;
  asm("v_exp_f32 %0, %1" : "=v"(r) : "v"(x));
  return r;
}

// HW trig: v_sin/v_cos take REVOLUTIONS; reduce via fract first.
static __device__ __forceinline__ void sincos_fast(float a, float* s, float* c) {
  const float INV2PI = 0.15915494309189535f;
  float r = a * INV2PI;
  r = r - floorf(r);
  float ss, cc;
  asm("v_sin_f32 %0, %1" : "=v"(ss) : "v"(r));
  asm("v_cos_f32 %0, %1" : "=v"(cc) : "v"(r));
  *s = ss;
  *c = cc;
}

// Per-block dtype detection with SPREAD probe addresses (one window per block).
// fp32 N(0,1) viewed as u16 words: mantissa-half words have uniform exponent
// field -> ~29%/word exceed 180; bf16 N(0,1) never exceeds ~130.
// All waves of a block read the same 64 dwords (tid&63) -> consistent verdict.
static __device__ __forceinline__ bool detect_f32_spread(const void* q, u32 blk) {
  const u32* q32 = (const u32*)q;
  u32 off = ((blk & 1023u) << 6) + (threadIdx.x & 63);  // < 64K dwords (256KB)
  u32 w0 = q32[off];
  u32 w1 = q32[off + 65536];  // second window 256KB away (< 8MB bf16 size)
  int big = ((((w0 >> 7) & 0xFF) > 180) | (((w0 >> 23) & 0xFF) > 180) |
             (((w1 >> 7) & 0xFF) > 180) | (((w1 >> 23) & 0xFF) > 180));
  return __ballot(big) != 0ULL;
}

// ---------- dtype detector kernel (fallback path only) ----------
__global__ void detect_dtype(const u16* __restrict__ q, int* __restrict__ flag) {
  int lane = threadIdx.x;  // 64
  int big = 0;
#pragma unroll
  for (int i = 0; i < 16; ++i) {
    u16 v = q[lane * 16 + i];
    int e = (v >> 7) & 0xFF;
    big |= (e > 180);
  }
  unsigned long long b = __ballot(big);
  if (lane == 0) *flag = (b != 0ULL) ? 1 : 0;
}

// load 8 consecutive elements as a bf16 fragment, converting from fp32 if f32.
static __device__ __forceinline__ bf16x8 ld8(const void* base, size_t off, bool f32) {
  if (f32) {
    const float* p = (const float*)base + off;
    float4 a = *(const float4*)p;
    float4 bb = *(const float4*)(p + 4);
    uint4 o;
    o.x = (u32)f2bf(a.x) | ((u32)f2bf(a.y) << 16);
    o.y = (u32)f2bf(a.z) | ((u32)f2bf(a.w) << 16);
    o.z = (u32)f2bf(bb.x) | ((u32)f2bf(bb.y) << 16);
    o.w = (u32)f2bf(bb.z) | ((u32)f2bf(bb.w) << 16);
    return __builtin_bit_cast(bf16x8, o);
  }
  return *(const bf16x8*)((const u16*)base + off);
}

// RoPE one 8-dim fragment covering dims quad*8..quad*8+7 (< ROT_W=32).
static __device__ __forceinline__ bf16x8 rope_frag(bf16x8 x, float pos, int quad) {
  uint4 u = __builtin_bit_cast(uint4, x);
  float v0 = bf2f((u16)u.x), v1 = bf2f((u16)(u.x >> 16));
  float v2 = bf2f((u16)u.y), v3 = bf2f((u16)(u.y >> 16));
  float v4 = bf2f((u16)u.z), v5 = bf2f((u16)(u.z >> 16));
  float v6 = bf2f((u16)u.w), v7 = bf2f((u16)(u.w >> 16));
  const float LB = 0.83048202372184058696f;  // log2(10000)/16
  float jb = (float)(quad * 4);
  float a0 = pos * exp2_fast(-jb * LB);
  float a1 = pos * exp2_fast(-(jb + 1.f) * LB);
  float a2 = pos * exp2_fast(-(jb + 2.f) * LB);
  float a3 = pos * exp2_fast(-(jb + 3.f) * LB);
  float s0, c0, s1, c1, s2, c2, s3, c3;
  sincos_fast(a0, &s0, &c0);
  sincos_fast(a1, &s1, &c1);
  sincos_fast(a2, &s2, &c2);
  sincos_fast(a3, &s3, &c3);
  uint4 o;
  o.x = (u32)f2bf(c0 * v0 - s0 * v1) | ((u32)f2bf(c0 * v1 + s0 * v0) << 16);
  o.y = (u32)f2bf(c1 * v2 - s1 * v3) | ((u32)f2bf(c1 * v3 + s1 * v2) << 16);
  o.z = (u32)f2bf(c2 * v4 - s2 * v5) | ((u32)f2bf(c2 * v5 + s2 * v4) << 16);
  o.w = (u32)f2bf(c3 * v6 - s3 * v7) | ((u32)f2bf(c3 * v7 + s3 * v6) << 16);
  return __builtin_bit_cast(bf16x8, o);
}

// ---------- merged prepass ----------
// K-RoPE -> Kr[bh][l][e] bf16 (row-contiguous per key; 4 rows per block to
// cut launch ramp), AND V -> VT[bh][vtile][e][k64] bf16 (8KB contiguous
// transposed tiles so flash's gll sources are 16-line coalesced).
__global__ __launch_bounds__(256) void prep_kv(
    const void* __restrict__ Q, const void* __restrict__ K, const void* __restrict__ V,
    u16* __restrict__ Kr, u16* __restrict__ VT) {
  __shared__ u16 tile[64][65];
  const int t = threadIdx.x;
  const bool f32 = detect_f32_spread(Q, blockIdx.x);

  if (blockIdx.x < (B_ * L_ / 4)) {
    // ---- K RoPE + (B,L,H,E) -> (B,H,L,E), 4 rows per block ----
    const int h = t >> 4, d = (t & 15) << 2;
#pragma unroll
    for (int i = 0; i < 4; ++i) {
      const int bl = (blockIdx.x << 2) + i;
      const int b = bl >> 11, l = bl & (L_ - 1);
      size_t in_off = (((size_t)(b * L_ + l) * H_ + h) * E_) + d;
      size_t out_off = (((size_t)(b * H_ + h) * L_ + l) * E_) + d;
      float k0, k1, k2, k3;
      if (f32) {
        float4 kv = *(const float4*)((const float*)K + in_off);
        k0 = kv.x; k1 = kv.y; k2 = kv.z; k3 = kv.w;
      } else {
        uint2 kv = *(const uint2*)((const u16*)K + in_off);
        k0 = bf2f((u16)kv.x); k1 = bf2f((u16)(kv.x >> 16));
        k2 = bf2f((u16)kv.y); k3 = bf2f((u16)(kv.y >> 16));
      }
      if (d < 32) {
        int j0 = d >> 1;
        const float LB = 0.83048202372184058696f;
        float a0 = (float)l * exp2_fast(-(float)j0 * LB);
        float a1 = (float)l * exp2_fast(-(float)(j0 + 1) * LB);
        float s0, c0, s1, c1;
        sincos_fast(a0, &s0, &c0);
        sincos_fast(a1, &s1, &c1);
        float r;
        r = c0 * k0 - s0 * k1; k1 = c0 * k1 + s0 * k0; k0 = r;
        r = c1 * k2 - s1 * k3; k3 = c1 * k3 + s1 * k2; k2 = r;
      }
      uint2 ko;
      ko.x = (u32)f2bf(k0) | ((u32)f2bf(k1) << 16);
      ko.y = (u32)f2bf(k2) | ((u32)f2bf(k3) << 16);
      *(uint2*)(Kr + out_off) = ko;
    }
  } else {
    // ---- V (B,L,H,E) -> VT tiled (B,H,vtile,E,64) ----
    const int blk = blockIdx.x - (B_ * L_ / 4);  // 0..1023
    const int bh = blk & 31, lt = blk >> 5;
    const int b = bh >> 4, h = bh & 15;
    const int l0 = lt << 6;
#pragma unroll
    for (int it = 0; it < 2; ++it) {
      int ll = (t >> 3) + (it << 5);
      int dc = (t & 7) << 3;
      size_t off = (((size_t)(b * L_ + l0 + ll) * H_ + h) * E_) + dc;
      bf16x8 x8 = ld8(V, off, f32);
      uint4 x = __builtin_bit_cast(uint4, x8);
      tile[ll][dc + 0] = (u16)x.x; tile[ll][dc + 1] = (u16)(x.x >> 16);
      tile[ll][dc + 2] = (u16)x.y; tile[ll][dc + 3] = (u16)(x.y >> 16);
      tile[ll][dc + 4] = (u16)x.z; tile[ll][dc + 5] = (u16)(x.z >> 16);
      tile[ll][dc + 6] = (u16)x.w; tile[ll][dc + 7] = (u16)(x.w >> 16);
    }
    __syncthreads();
    int e = t >> 2, lg = (t & 3) << 4;
    u32 pk[8];
#pragma unroll
    for (int i = 0; i < 8; ++i)
      pk[i] = (u32)tile[lg + 2 * i][e] | ((u32)tile[lg + 2 * i + 1][e] << 16);
    // tiled dst: VT[(bh*32+lt)*4096 + e*64 + k]
    u16* dst = VT + (((size_t)(bh * 32 + lt)) << 12) + e * 64 + lg;
    uint4 o0; o0.x = pk[0]; o0.y = pk[1]; o0.z = pk[2]; o0.w = pk[3];
    uint4 o1; o1.x = pk[4]; o1.y = pk[5]; o1.z = pk[6]; o1.w = pk[7];
    *(uint4*)dst = o0;
    *(uint4*)(dst + 8) = o1;
  }
}

#if __has_builtin(__builtin_amdgcn_global_load_lds)
#define HAS_GLL 1
// Direct global->LDS DMA, 16B/lane. LDS dest is wave-uniform base + lane*16;
// global source is per-lane (pre-swizzled).
static __device__ __forceinline__ void gll16(const void* g, void* l) {
  __builtin_amdgcn_global_load_lds(
      (const __attribute__((address_space(1))) u32*)g,
      (__attribute__((address_space(3))) u32*)l, 16, 0, 0);
}
#else
#define HAS_GLL 0
#endif

// ---------- main flash kernel v10 = proven v8 + pipe-work trims ----------
// R9 post-mortem: bpermute P-transpose needs 8 bpermutes+4 selects (one
// source value per lane per instr; each producer serves two consumers with
// different ch) -> 24 DS ops/var vs LDS round-trip's 9 -> abandoned.
// Pipe model of v8 (812 cyc/var-unit @4waves/SIMD): MFMA 135, VALU ~250,
// DS ~300 -> near sum-of-pipes. v10 trims work on the busy pipes:
//  * vf0 hoisted: tiles cc[0]/cc[1] share the same 4 V fragments
//    (-4 ds_read_b128/var).
//  * mask via precomputed mbias[ch][reg] in {0,-inf} added to the score
//    (exp2(-inf)=0) instead of per-reg cmp+cndmask.
// Everything else identical to R8's passing flash_v8 (incl. the 3 proven
// lgkmcnt(0) drains).
__global__ __launch_bounds__(512, 2) void flash_v10(
    const void* __restrict__ Q, const u16* __restrict__ Kr,
    const u16* __restrict__ VT, const void* __restrict__ bw,
    void* __restrict__ out) {
  __shared__ u16 kbuf[2][2][64][64];  // [half][dbuf][key][dim], 16B-col-swizzled
  __shared__ u16 vbuf[2][2][64][64];  // [half][dbuf][dim e][key], swizzled
  __shared__ u32 plds[8][16][20];     // per-wave P exchange (single 16-row region)

  const int tid = threadIdx.x;
  const int wid = tid >> 6, lane = tid & 63;
  const int half = wid >> 2, w4 = wid & 3;
  const int quad = lane >> 4, l16 = lane & 15;
  const int bh = blockIdx.x & 31;  // low bits -> all blocks of a bh on one XCD
  const int gb = blockIdx.x >> 5;  // 0..15
  const int var_l = (gb << 1) + (w4 >> 1);
  const int s0 = (w4 & 1) << 4;
  const int base = var_l << 6;
  const int b = bh >> 4, h = bh & 15;

  const bool f32 = detect_f32_spread(Q, blockIdx.x);
  const u16* Kb = Kr + ((size_t)bh << 17);
  const u16* Vb = VT + ((size_t)bh << 17);  // 32 tiles x 4096 elems

  const float LOG2E = 1.4426950408889634f;
  const float bw_diff = f32 ? ((const float*)bw)[h] : bf2f(((const u16*)bw)[h]);
  const float bw_same = f32 ? ((const float*)bw)[H_ + h] : bf2f(((const u16*)bw)[H_ + h]);
  const float C1 = 0.125f * LOG2E;
  const float c2d = bw_diff * LOG2E;
  const float c2s = bw_same * LOG2E;
  const float NEGINF = -__builtin_inff();

  // Precomputed causal-mask bias for diag tiles: key-time (mod 32) of slot
  // (ch,reg) vs query-time (mod 32) of this lane. -inf -> exp2 = 0.
  float mbias[2][4];
#pragma unroll
  for (int ch = 0; ch < 2; ++ch)
#pragma unroll
    for (int reg = 0; reg < 4; ++reg)
      mbias[ch][reg] = ((ch * 16 + quad * 4 + reg) > (s0 + l16)) ? NEGINF : 0.0f;

  // Q fragments (MFMA B-operand, n=query=l16), RoPE'd in-register.
  bf16x8 qf[2][2];
#pragma unroll
  for (int rh = 0; rh < 2; ++rh) {
    const int r = base + s0 + (rh << 5) + l16;
    size_t ro = (((size_t)(b * L_ + r) * H_ + h) * E_);
    qf[rh][0] = rope_frag(ld8(Q, ro + quad * 8, f32), (float)r, quad);
    qf[rh][1] = ld8(Q, ro + 32 + quad * 8, f32);
  }

  const floatx4 zero4 = {0.f, 0.f, 0.f, 0.f};
  bf16x8 ones;
  { uint4 t4; t4.x = t4.y = t4.z = t4.w = 0x3F803F80u; ones = __builtin_bit_cast(bf16x8, t4); }

  floatx4 oacc[2][4], lacc[2];
#pragma unroll
  for (int rh = 0; rh < 2; ++rh) {
    lacc[rh] = zero4;
#pragma unroll
    for (int c4 = 0; c4 < 4; ++c4) oacc[rh][c4] = zero4;
  }

  // staging: 8 chunks of 1KB per 8KB tile; wave w4 does chunks 2w4,2w4+1 of
  // ITS half's kbuf and vbuf (4 gll16/wave/var).
  const int srow = lane >> 3;          // row-within-chunk 0..7 (= row&7)
  const int sc16 = (lane & 7) ^ srow;  // pre-swizzled global 16B column
#if !HAS_GLL
  uint4 sk[2], sv[2];
#endif
  auto stage_issue = [&](int bufn, int v) {
    const int k0r = v << 6;
#pragma unroll
    for (int rr = 0; rr < 2; ++rr) {
      const int chunk = (w4 << 1) + rr;
      const int row = (chunk << 3) + srow;
      const u16* gk = Kb + (size_t)(k0r + row) * 64 + sc16 * 8;
      const u16* gv = Vb + ((size_t)v << 12) + (size_t)row * 64 + sc16 * 8;
#if HAS_GLL
      gll16(gk, (char*)&kbuf[half][bufn][0][0] + chunk * 1024);
      gll16(gv, (char*)&vbuf[half][bufn][0][0] + chunk * 1024);
#else
      sk[rr] = *(const uint4*)gk;
      sv[rr] = *(const uint4*)gv;
#endif
    }
  };
  auto stage_commit = [&](int bufn) {
#if !HAS_GLL
#pragma unroll
    for (int rr = 0; rr < 2; ++rr) {
      const int chunk = (w4 << 1) + rr;
      *(uint4*)((u16*)&kbuf[half][bufn][0][0] + chunk * 512 + lane * 8) = sk[rr];
      *(uint4*)((u16*)&vbuf[half][bufn][0][0] + chunk * 512 + lane * 8) = sv[rr];
    }
#else
    (void)bufn;
#endif
  };

  const int vbase = half << 4;
  stage_issue(0, vbase);
  stage_commit(0);
  __asm__ volatile("s_waitcnt vmcnt(0)" ::: "memory");
  __syncthreads();

  const int sw = l16 & 7;  // read-side swizzle key (row&7 == l16&7 for all reads)
  u32* const prow = &plds[wid][l16][0];

  // one 32-key tile: softmax + P exchange + rowsum + PV (vf passed in).
  auto pv_tile = [&](const floatx4 sc[2], bool msk_on, float c2,
                     int rh, const bf16x8 vf[4]) {
#pragma unroll
    for (int ch = 0; ch < 2; ++ch) {
      float p[4];
#pragma unroll
      for (int reg = 0; reg < 4; ++reg) {
        float s = fmaf(sc[ch][reg], C1, c2);
        if (msk_on) s += mbias[ch][reg];  // {0,-inf}: exp2(-inf)=0
        p[reg] = exp2_fast(s);
      }
      uint2 w;
      w.x = cvtpk_bf16(p[0], p[1]);
      w.y = cvtpk_bf16(p[2], p[3]);
      *(uint2*)(prow + ch * 8 + quad * 2) = w;  // ds_write_b64
    }
    __asm__ volatile("s_waitcnt lgkmcnt(0)" ::: "memory");
    bf16x8 pa = __builtin_bit_cast(bf16x8, *(const uint4*)(prow + quad * 4));
    __builtin_amdgcn_s_setprio(1);
    lacc[rh] = __builtin_amdgcn_mfma_f32_16x16x32_bf16(pa, ones, lacc[rh], 0, 0, 0);
#pragma unroll
    for (int c4 = 0; c4 < 4; ++c4)
      oacc[rh][c4] = __builtin_amdgcn_mfma_f32_16x16x32_bf16(pa, vf[c4], oacc[rh][c4], 0, 0, 0);
    __builtin_amdgcn_s_setprio(0);
  };

  for (int vi = 0; vi < 16; ++vi) {
    const int v = vbase + vi;
    const int buf = vi & 1;
    const bool more = (vi < 15);
    if (more) stage_issue(buf ^ 1, v + 1);  // prefetch next tile

    const float c2 = (v == var_l) ? c2s : c2d;

    // ---- kt0: load kf, QK for both rh, then kf dies ----
    floatx4 cc[2][2];
    {
      bf16x8 kf[2][2];
#pragma unroll
      for (int ch = 0; ch < 2; ++ch) {
        const int row = ch * 16 + l16;
#pragma unroll
        for (int hf = 0; hf < 2; ++hf)
          kf[ch][hf] = *(const bf16x8*)&kbuf[half][buf][row][(((hf << 2) + quad) ^ sw) << 3];
      }
      __builtin_amdgcn_s_setprio(1);
#pragma unroll
      for (int ch = 0; ch < 2; ++ch)
#pragma unroll
        for (int rh = 0; rh < 2; ++rh) {
          floatx4 a0 = __builtin_amdgcn_mfma_f32_16x16x32_bf16(kf[ch][0], qf[rh][0], zero4, 0, 0, 0);
          cc[rh][ch] = __builtin_amdgcn_mfma_f32_16x16x32_bf16(kf[ch][1], qf[rh][1], a0, 0, 0, 0);
        }
      __builtin_amdgcn_s_setprio(0);
    }
    // ---- kt1: load kg (after kf freed), QK for rh1, kg dies ----
    floatx4 dd[2];
    {
      bf16x8 kg[2][2];
#pragma unroll
      for (int ch = 0; ch < 2; ++ch) {
        const int row = 32 + ch * 16 + l16;
#pragma unroll
        for (int hf = 0; hf < 2; ++hf)
          kg[ch][hf] = *(const bf16x8*)&kbuf[half][buf][row][(((hf << 2) + quad) ^ sw) << 3];
      }
      __builtin_amdgcn_s_setprio(1);
#pragma unroll
      for (int ch = 0; ch < 2; ++ch) {
        floatx4 a1 = __builtin_amdgcn_mfma_f32_16x16x32_bf16(kg[ch][0], qf[1][0], zero4, 0, 0, 0);
        dd[ch] = __builtin_amdgcn_mfma_f32_16x16x32_bf16(kg[ch][1], qf[1][1], a1, 0, 0, 0);
      }
      __builtin_amdgcn_s_setprio(0);
    }

    // tiles 1-2 (keys k0..k0+31) share the SAME V fragments: load once.
    {
      bf16x8 vf0[4];
#pragma unroll
      for (int c4 = 0; c4 < 4; ++c4)
        vf0[c4] = *(const bf16x8*)&vbuf[half][buf][c4 * 16 + l16][(quad ^ sw) << 3];
      pv_tile(cc[0], true, c2, 0, vf0);   // rh0 x kt0 (diag-masked)
      pv_tile(cc[1], false, c2, 1, vf0);  // rh1 x kt0 (full)
    }
    // tile 3 (keys k0+32..k0+63)
    {
      bf16x8 vf1[4];
#pragma unroll
      for (int c4 = 0; c4 < 4; ++c4)
        vf1[c4] = *(const bf16x8*)&vbuf[half][buf][c4 * 16 + l16][((4 + quad) ^ sw) << 3];
      pv_tile(dd, true, c2, 1, vf1);      // rh1 x kt1 (diag-masked)
    }

    if (more) {
      stage_commit(buf ^ 1);
      __asm__ volatile("s_waitcnt vmcnt(0)" ::: "memory");
      __syncthreads();
    }
  }

  // ---- split-K combine: halves' partials simply add (static softmax) ----
  __syncthreads();  // retire last tile's LDS use; kbuf/vbuf space is now free
  float* oscr = (float*)&kbuf[0][0][0][0];  // 32KB = 8192 floats (2 waves/round)
  float* lscr = (float*)&vbuf[0][0][0][0];  // 4KB used
#pragma unroll
  for (int round = 0; round < 2; ++round) {
    const int src0 = 4 + (round << 1);
    if (wid == src0 || wid == src0 + 1) {
      const int slot = wid - src0;
      float* dst = oscr + slot * 4096;
#pragma unroll
      for (int rh = 0; rh < 2; ++rh) {
#pragma unroll
        for (int c4 = 0; c4 < 4; ++c4)
          *(floatx4*)(dst + (rh * 4 + c4) * 256 + lane * 4) = oacc[rh][c4];
        *(floatx4*)(lscr + slot * 512 + lane * 8 + rh * 4) = lacc[rh];
      }
    }
    __syncthreads();
    const int dst0 = round << 1;
    if (wid == dst0 || wid == dst0 + 1) {
      const int slot = wid - dst0;
      const float* src = oscr + slot * 4096;
#pragma unroll
      for (int rh = 0; rh < 2; ++rh) {
#pragma unroll
        for (int c4 = 0; c4 < 4; ++c4)
          oacc[rh][c4] += *(const floatx4*)(src + (rh * 4 + c4) * 256 + lane * 4);
        lacc[rh] += *(const floatx4*)(lscr + slot * 512 + lane * 8 + rh * 4);
      }
    }
    __syncthreads();
  }

  if (half == 0) {
    float rinv[2][4];
#pragma unroll
    for (int rh = 0; rh < 2; ++rh)
#pragma unroll
      for (int reg = 0; reg < 4; ++reg) {
        float lv = lacc[rh][reg];
        rinv[rh][reg] = (lv > 1e-30f) ? 1.0f / lv : 0.0f;
      }
#pragma unroll
    for (int rh = 0; rh < 2; ++rh)
#pragma unroll
      for (int c4 = 0; c4 < 4; ++c4)
#pragma unroll
        for (int reg = 0; reg < 4; ++reg) {
          const int row = base + s0 + (rh << 5) + quad * 4 + reg;
          const int col = c4 * 16 + l16;
          float val = oacc[rh][c4][reg] * rinv[rh][reg];
          size_t oo = (((size_t)(b * L_ + row)) * H_ + h) * E_ + col;
          if (f32) ((float*)out)[oo] = val;
          else ((u16*)out)[oo] = f2bf(val);
        }
  }
}

// ---------- fully-fused fallback (tiny/absent workspace): RoPE + V-transpose in-loop ----------
__global__ __launch_bounds__(256) void flash_fused(
    const void* __restrict__ Q, const void* __restrict__ K,
    const void* __restrict__ V, const void* __restrict__ bw,
    const int* __restrict__ flag, void* __restrict__ out) {
  __shared__ u16 plds[4][2][32 * 36];
  __shared__ u16 vlds[4][64][40];
  const bool f32 = flag ? (*flag != 0) : true;
  const int tid = threadIdx.x;
  const int wid = tid >> 6, lane = tid & 63;
  const int quad = lane >> 4, l16 = lane & 15;
  const int bh = blockIdx.x & 31;
  const int g = blockIdx.x >> 5;
  const int rowblk = (g << 2) + wid;
  const int row0 = rowblk << 5;
  const int b = bh >> 4, h = bh & 15;
  const int t0 = row0 & 63;
  const int var_l = row0 >> 6;
  const int ktiles = (t0 >> 5) + 1;

  const float bw_diff = f32 ? ((const float*)bw)[h] : bf2f(((const u16*)bw)[h]);
  const float bw_same = f32 ? ((const float*)bw)[H_ + h] : bf2f(((const u16*)bw)[H_ + h]);

  const floatx4 zero4 = {0.f, 0.f, 0.f, 0.f};
  bf16x8 ones;
  { uint4 t4; t4.x = t4.y = t4.z = t4.w = 0x3F803F80u; ones = __builtin_bit_cast(bf16x8, t4); }

  bf16x8 qf[2][2];
#pragma unroll
  for (int rh = 0; rh < 2; ++rh) {
    const int r = row0 + rh * 16 + l16;
    size_t ro = (((size_t)(b * L_ + r) * H_ + h) * E_);
#pragma unroll
    for (int hf = 0; hf < 2; ++hf)
      qf[rh][hf] = ld8(Q, ro + hf * 32 + quad * 8, f32);
    qf[rh][0] = rope_frag(qf[rh][0], (float)r, quad);
  }

  floatx4 oacc[2][4], lacc[2];
#pragma unroll
  for (int rh = 0; rh < 2; ++rh) {
    lacc[rh] = zero4;
#pragma unroll
    for (int c4 = 0; c4 < 4; ++c4) oacc[rh][c4] = zero4;
  }

  u16* const pbase = &plds[wid][0][0];
  u16* const vb = &vlds[wid][0][0];
  int pp = 0;

  for (int v = 0; v < 32; ++v) {
    const float bias = (v == var_l) ? bw_same : bw_diff;
    for (int kt = 0; kt < ktiles; ++kt) {
      const int k0 = (v << 6) + (kt << 5);

      bf16x8 kf[2][2];
#pragma unroll
      for (int ch = 0; ch < 2; ++ch) {
        const int r = k0 + ch * 16 + l16;
        size_t ro = (((size_t)(b * L_ + r) * H_ + h) * E_);
#pragma unroll
        for (int hf = 0; hf < 2; ++hf)
          kf[ch][hf] = ld8(K, ro + hf * 32 + quad * 8, f32);
        kf[ch][0] = rope_frag(kf[ch][0], (float)r, quad);
      }

      floatx4 cc[2][2];
#pragma unroll
      for (int rh = 0; rh < 2; ++rh)
#pragma unroll
        for (int ch = 0; ch < 2; ++ch) {
          floatx4 acc = __builtin_amdgcn_mfma_f32_16x16x32_bf16(qf[rh][0], kf[ch][0], zero4, 0, 0, 0);
          cc[rh][ch] = __builtin_amdgcn_mfma_f32_16x16x32_bf16(qf[rh][1], kf[ch][1], acc, 0, 0, 0);
        }

      u16* const pw = pbase + pp * (32 * 36);
      const int ts_b = (kt << 5) + l16;
#pragma unroll
      for (int rh = 0; rh < 2; ++rh)
#pragma unroll
        for (int ch = 0; ch < 2; ++ch) {
          const int ts = ts_b + ch * 16;
#pragma unroll
          for (int reg = 0; reg < 4; ++reg) {
            const int tl = t0 + rh * 16 + quad * 4 + reg;
            float s = cc[rh][ch][reg] * 0.125f + bias;
            float p = (ts > tl) ? 0.0f : __expf(s);
            pw[(rh * 16 + quad * 4 + reg) * 36 + ch * 16 + l16] = f2bf(p);
          }
        }

      // stage V tile (32 keys x 64 dims) transposed into LDS
#pragma unroll
      for (int it = 0; it < 4; ++it) {
        const int s = (lane >> 3) + it * 8;
        const int dc = (lane & 7) << 3;
        size_t vo = (((size_t)(b * L_ + k0 + s) * H_ + h) * E_) + dc;
        bf16x8 x8 = ld8(V, vo, f32);
        uint4 x = __builtin_bit_cast(uint4, x8);
        vb[(dc + 0) * 40 + s] = (u16)x.x; vb[(dc + 1) * 40 + s] = (u16)(x.x >> 16);
        vb[(dc + 2) * 40 + s] = (u16)x.y; vb[(dc + 3) * 40 + s] = (u16)(x.y >> 16);
        vb[(dc + 4) * 40 + s] = (u16)x.z; vb[(dc + 5) * 40 + s] = (u16)(x.z >> 16);
        vb[(dc + 6) * 40 + s] = (u16)x.w; vb[(dc + 7) * 40 + s] = (u16)(x.w >> 16);
      }

      __asm__ volatile("s_waitcnt lgkmcnt(0)" ::: "memory");

      bf16x8 pa[2];
#pragma unroll
      for (int rh = 0; rh < 2; ++rh) {
        const u16* pr = pw + (rh * 16 + l16) * 36 + quad * 8;
        uint2 lo = *(const uint2*)pr;
        uint2 hi = *(const uint2*)(pr + 4);
        uint4 cmb; cmb.x = lo.x; cmb.y = lo.y; cmb.z = hi.x; cmb.w = hi.y;
        pa[rh] = __builtin_bit_cast(bf16x8, cmb);
      }

#pragma unroll
      for (int rh = 0; rh < 2; ++rh)
        lacc[rh] = __builtin_amdgcn_mfma_f32_16x16x32_bf16(pa[rh], ones, lacc[rh], 0, 0, 0);

#pragma unroll
      for (int c4 = 0; c4 < 4; ++c4) {
        bf16x8 vf = *(const bf16x8*)(vb + (c4 * 16 + l16) * 40 + quad * 8);
#pragma unroll
        for (int rh = 0; rh < 2; ++rh)
          oacc[rh][c4] = __builtin_amdgcn_mfma_f32_16x16x32_bf16(pa[rh], vf, oacc[rh][c4], 0, 0, 0);
      }
      pp ^= 1;
    }
  }

  float rinv[2][4];
#pragma unroll
  for (int rh = 0; rh < 2; ++rh)
#pragma unroll
    for (int reg = 0; reg < 4; ++reg) {
      float lv = lacc[rh][reg];
      rinv[rh][reg] = (lv > 1e-30f) ? 1.0f / lv : 0.0f;
    }

#pragma unroll
  for (int rh = 0; rh < 2; ++rh)
#pragma unroll
    for (int c4 = 0; c4 < 4; ++c4)
#pragma unroll
      for (int reg = 0; reg < 4; ++reg) {
        const int row = row0 + rh * 16 + quad * 4 + reg;
        const int col = c4 * 16 + l16;
        float val = oacc[rh][c4][reg] * rinv[rh][reg];
        size_t oo = (((size_t)(b * L_ + row)) * H_ + h) * E_ + col;
        if (f32) ((float*)out)[oo] = val;
        else ((u16*)out)[oo] = f2bf(val);
      }
}

extern "C" void kernel_launch(void* const* d_in, const int* in_sizes, int n_in,
                              void* d_out, int out_size, void* d_ws, size_t ws_size,
                              hipStream_t stream) {
  (void)in_sizes; (void)n_in; (void)out_size;
  const void* q = d_in[0];
  const void* k = d_in[1];
  const void* v = d_in[2];
  const void* bwp = d_in[3];
  // d_in[4]=n_vars(=32), d_in[5]=n_tokens(=64): fixed by setup, hardcoded.
  const size_t need = (size_t)WS_OFF * 2 + 2u * QK_ELEMS * sizeof(u16);  // ~16.8 MB
  if (ws_size >= need) {
    u16* Kr = (u16*)d_ws + WS_OFF;
    u16* VT = Kr + QK_ELEMS;
    prep_kv<<<B_ * L_ / 4 + B_ * H_ * (L_ / 64), 256, 0, stream>>>(q, k, v, Kr, VT);
    flash_v10<<<512, 512, 0, stream>>>(q, Kr, VT, bwp, d_out);
  } else if (ws_size >= sizeof(int)) {
    int* flag = (int*)d_ws;
    detect_dtype<<<1, 64, 0, stream>>>((const u16*)q, flag);
    flash_fused<<<512, 256, 0, stream>>>(q, k, v, bwp, flag, d_out);
  } else {
    flash_fused<<<512, 256, 0, stream>>>(q, k, v, bwp, (const int*)nullptr, d_out);
  }
}

// Round 11
// 136.969 us; speedup vs baseline: 1.0998x; 1.0998x over previous
//
#include <hip/hip_runtime.h>

typedef unsigned short u16;
typedef unsigned int u32;

typedef __attribute__((ext_vector_type(8))) __bf16 bf16x8;
typedef __attribute__((ext_vector_type(4))) float floatx4;

#define B_ 2
#define L_ 2048
#define H_ 16
#define E_ 64
#define QK_ELEMS (B_ * H_ * L_ * E_) /* 4194304 elements */
#define WS_OFF 128                   /* staged tensors at +128 elems into ws */

static __device__ __forceinline__ float bf2f(u16 v) {
  u32 u = ((u32)v) << 16;
  return __builtin_bit_cast(float, u);
}
static __device__ __forceinline__ u16 f2bf(float x) {
  u32 u = __builtin_bit_cast(u32, x);
  u32 r = (u + 0x7FFFu + ((u >> 16) & 1u)) >> 16;
  return (u16)r;
}

// packed f32->bf16 (RNE): dst[15:0]=bf16(lo), dst[31:16]=bf16(hi)
static __device__ __forceinline__ u32 cvtpk_bf16(float lo, float hi) {
  u32 r;
  asm("v_cvt_pk_bf16_f32 %0, %1, %2" : "=v"(r) : "v"(lo), "v"(hi));
  return r;
}

static __device__ __forceinline__ float exp2_fast(float x) {
  float r;
  asm("v_exp_f32 %0, %1" : "=v"(r) : "v"(x));
  return r;
}

// HW trig: v_sin/v_cos take REVOLUTIONS; reduce via fract first.
static __device__ __forceinline__ void sincos_fast(float a, float* s, float* c) {
  const float INV2PI = 0.15915494309189535f;
  float r = a * INV2PI;
  r = r - floorf(r);
  float ss, cc;
  asm("v_sin_f32 %0, %1" : "=v"(ss) : "v"(r));
  asm("v_cos_f32 %0, %1" : "=v"(cc) : "v"(r));
  *s = ss;
  *c = cc;
}

// Per-block dtype detection with SPREAD probe addresses (one window per block).
// fp32 N(0,1) viewed as u16 words: mantissa-half words have uniform exponent
// field -> ~29%/word exceed 180; bf16 N(0,1) never exceeds ~130.
// All waves of a block read the same 64 dwords (tid&63) -> consistent verdict.
static __device__ __forceinline__ bool detect_f32_spread(const void* q, u32 blk) {
  const u32* q32 = (const u32*)q;
  u32 off = ((blk & 1023u) << 6) + (threadIdx.x & 63);  // < 64K dwords (256KB)
  u32 w0 = q32[off];
  u32 w1 = q32[off + 65536];  // second window 256KB away (< 8MB bf16 size)
  int big = ((((w0 >> 7) & 0xFF) > 180) | (((w0 >> 23) & 0xFF) > 180) |
             (((w1 >> 7) & 0xFF) > 180) | (((w1 >> 23) & 0xFF) > 180));
  return __ballot(big) != 0ULL;
}

// ---------- dtype detector kernel (fallback path only) ----------
__global__ void detect_dtype(const u16* __restrict__ q, int* __restrict__ flag) {
  int lane = threadIdx.x;  // 64
  int big = 0;
#pragma unroll
  for (int i = 0; i < 16; ++i) {
    u16 v = q[lane * 16 + i];
    int e = (v >> 7) & 0xFF;
    big |= (e > 180);
  }
  unsigned long long b = __ballot(big);
  if (lane == 0) *flag = (b != 0ULL) ? 1 : 0;
}

// load 8 consecutive elements as a bf16 fragment, converting from fp32 if f32.
static __device__ __forceinline__ bf16x8 ld8(const void* base, size_t off, bool f32) {
  if (f32) {
    const float* p = (const float*)base + off;
    float4 a = *(const float4*)p;
    float4 bb = *(const float4*)(p + 4);
    uint4 o;
    o.x = (u32)f2bf(a.x) | ((u32)f2bf(a.y) << 16);
    o.y = (u32)f2bf(a.z) | ((u32)f2bf(a.w) << 16);
    o.z = (u32)f2bf(bb.x) | ((u32)f2bf(bb.y) << 16);
    o.w = (u32)f2bf(bb.z) | ((u32)f2bf(bb.w) << 16);
    return __builtin_bit_cast(bf16x8, o);
  }
  return *(const bf16x8*)((const u16*)base + off);
}

// RoPE one 8-dim fragment covering dims quad*8..quad*8+7 (< ROT_W=32).
static __device__ __forceinline__ bf16x8 rope_frag(bf16x8 x, float pos, int quad) {
  uint4 u = __builtin_bit_cast(uint4, x);
  float v0 = bf2f((u16)u.x), v1 = bf2f((u16)(u.x >> 16));
  float v2 = bf2f((u16)u.y), v3 = bf2f((u16)(u.y >> 16));
  float v4 = bf2f((u16)u.z), v5 = bf2f((u16)(u.z >> 16));
  float v6 = bf2f((u16)u.w), v7 = bf2f((u16)(u.w >> 16));
  const float LB = 0.83048202372184058696f;  // log2(10000)/16
  float jb = (float)(quad * 4);
  float a0 = pos * exp2_fast(-jb * LB);
  float a1 = pos * exp2_fast(-(jb + 1.f) * LB);
  float a2 = pos * exp2_fast(-(jb + 2.f) * LB);
  float a3 = pos * exp2_fast(-(jb + 3.f) * LB);
  float s0, c0, s1, c1, s2, c2, s3, c3;
  sincos_fast(a0, &s0, &c0);
  sincos_fast(a1, &s1, &c1);
  sincos_fast(a2, &s2, &c2);
  sincos_fast(a3, &s3, &c3);
  uint4 o;
  o.x = (u32)f2bf(c0 * v0 - s0 * v1) | ((u32)f2bf(c0 * v1 + s0 * v0) << 16);
  o.y = (u32)f2bf(c1 * v2 - s1 * v3) | ((u32)f2bf(c1 * v3 + s1 * v2) << 16);
  o.z = (u32)f2bf(c2 * v4 - s2 * v5) | ((u32)f2bf(c2 * v5 + s2 * v4) << 16);
  o.w = (u32)f2bf(c3 * v6 - s3 * v7) | ((u32)f2bf(c3 * v7 + s3 * v6) << 16);
  return __builtin_bit_cast(bf16x8, o);
}

// ---------- merged prepass ----------
// K-RoPE -> Kr[bh][l][e] bf16 (row-contiguous per key; 4 rows per block to
// cut launch ramp), AND V -> VT[bh][vtile][e][k64] bf16 (8KB contiguous
// transposed tiles so flash's gll sources are 16-line coalesced).
__global__ __launch_bounds__(256) void prep_kv(
    const void* __restrict__ Q, const void* __restrict__ K, const void* __restrict__ V,
    u16* __restrict__ Kr, u16* __restrict__ VT) {
  __shared__ u16 tile[64][65];
  const int t = threadIdx.x;
  const bool f32 = detect_f32_spread(Q, blockIdx.x);

  if (blockIdx.x < (B_ * L_ / 4)) {
    // ---- K RoPE + (B,L,H,E) -> (B,H,L,E), 4 rows per block ----
    const int h = t >> 4, d = (t & 15) << 2;
#pragma unroll
    for (int i = 0; i < 4; ++i) {
      const int bl = (blockIdx.x << 2) + i;
      const int b = bl >> 11, l = bl & (L_ - 1);
      size_t in_off = (((size_t)(b * L_ + l) * H_ + h) * E_) + d;
      size_t out_off = (((size_t)(b * H_ + h) * L_ + l) * E_) + d;
      float k0, k1, k2, k3;
      if (f32) {
        float4 kv = *(const float4*)((const float*)K + in_off);
        k0 = kv.x; k1 = kv.y; k2 = kv.z; k3 = kv.w;
      } else {
        uint2 kv = *(const uint2*)((const u16*)K + in_off);
        k0 = bf2f((u16)kv.x); k1 = bf2f((u16)(kv.x >> 16));
        k2 = bf2f((u16)kv.y); k3 = bf2f((u16)(kv.y >> 16));
      }
      if (d < 32) {
        int j0 = d >> 1;
        const float LB = 0.83048202372184058696f;
        float a0 = (float)l * exp2_fast(-(float)j0 * LB);
        float a1 = (float)l * exp2_fast(-(float)(j0 + 1) * LB);
        float s0, c0, s1, c1;
        sincos_fast(a0, &s0, &c0);
        sincos_fast(a1, &s1, &c1);
        float r;
        r = c0 * k0 - s0 * k1; k1 = c0 * k1 + s0 * k0; k0 = r;
        r = c1 * k2 - s1 * k3; k3 = c1 * k3 + s1 * k2; k2 = r;
      }
      uint2 ko;
      ko.x = (u32)f2bf(k0) | ((u32)f2bf(k1) << 16);
      ko.y = (u32)f2bf(k2) | ((u32)f2bf(k3) << 16);
      *(uint2*)(Kr + out_off) = ko;
    }
  } else {
    // ---- V (B,L,H,E) -> VT tiled (B,H,vtile,E,64) ----
    const int blk = blockIdx.x - (B_ * L_ / 4);  // 0..1023
    const int bh = blk & 31, lt = blk >> 5;
    const int b = bh >> 4, h = bh & 15;
    const int l0 = lt << 6;
#pragma unroll
    for (int it = 0; it < 2; ++it) {
      int ll = (t >> 3) + (it << 5);
      int dc = (t & 7) << 3;
      size_t off = (((size_t)(b * L_ + l0 + ll) * H_ + h) * E_) + dc;
      bf16x8 x8 = ld8(V, off, f32);
      uint4 x = __builtin_bit_cast(uint4, x8);
      tile[ll][dc + 0] = (u16)x.x; tile[ll][dc + 1] = (u16)(x.x >> 16);
      tile[ll][dc + 2] = (u16)x.y; tile[ll][dc + 3] = (u16)(x.y >> 16);
      tile[ll][dc + 4] = (u16)x.z; tile[ll][dc + 5] = (u16)(x.z >> 16);
      tile[ll][dc + 6] = (u16)x.w; tile[ll][dc + 7] = (u16)(x.w >> 16);
    }
    __syncthreads();
    int e = t >> 2, lg = (t & 3) << 4;
    u32 pk[8];
#pragma unroll
    for (int i = 0; i < 8; ++i)
      pk[i] = (u32)tile[lg + 2 * i][e] | ((u32)tile[lg + 2 * i + 1][e] << 16);
    // tiled dst: VT[(bh*32+lt)*4096 + e*64 + k]
    u16* dst = VT + (((size_t)(bh * 32 + lt)) << 12) + e * 64 + lg;
    uint4 o0; o0.x = pk[0]; o0.y = pk[1]; o0.z = pk[2]; o0.w = pk[3];
    uint4 o1; o1.x = pk[4]; o1.y = pk[5]; o1.z = pk[6]; o1.w = pk[7];
    *(uint4*)dst = o0;
    *(uint4*)(dst + 8) = o1;
  }
}

#if __has_builtin(__builtin_amdgcn_global_load_lds)
#define HAS_GLL 1
// Direct global->LDS DMA, 16B/lane. LDS dest is wave-uniform base + lane*16;
// global source is per-lane (pre-swizzled).
static __device__ __forceinline__ void gll16(const void* g, void* l) {
  __builtin_amdgcn_global_load_lds(
      (const __attribute__((address_space(1))) u32*)g,
      (__attribute__((address_space(3))) u32*)l, 16, 0, 0);
}
#else
#define HAS_GLL 0
#endif

// ---------- main flash kernel v11 = proven v8 + compiler-only P fence ----------
// R10 post-mortem: hoisting V reads before the P-writes serialized them INTO
// the lgkmcnt(0) drain (52->64us). Reverted: v11 is v8 verbatim except ONE
// change: the per-tile "s_waitcnt lgkmcnt(0)" instruction is replaced by a
// PURE COMPILER FENCE (empty asm + memory clobber, zero instructions).
// Rationale: the per-wave LDS pipe is in-order, so a ds_read issued after a
// ds_write to the same address returns the written data with no architectural
// wait; the read's register dependency gets an automatic counted lgkmcnt from
// the compiler. The fence only prevents compiler reordering of the read
// before the writes. Removes 48 full-pipe drains per wave and lets kf/kg/vf
// reads pipeline across tiles with counted waits.
__global__ __launch_bounds__(512, 2) void flash_v11(
    const void* __restrict__ Q, const u16* __restrict__ Kr,
    const u16* __restrict__ VT, const void* __restrict__ bw,
    void* __restrict__ out) {
  __shared__ u16 kbuf[2][2][64][64];  // [half][dbuf][key][dim], 16B-col-swizzled
  __shared__ u16 vbuf[2][2][64][64];  // [half][dbuf][dim e][key], swizzled
  __shared__ u32 plds[8][16][20];     // per-wave P exchange (single 16-row region)

  const int tid = threadIdx.x;
  const int wid = tid >> 6, lane = tid & 63;
  const int half = wid >> 2, w4 = wid & 3;
  const int quad = lane >> 4, l16 = lane & 15;
  const int bh = blockIdx.x & 31;  // low bits -> all blocks of a bh on one XCD
  const int gb = blockIdx.x >> 5;  // 0..15
  const int var_l = (gb << 1) + (w4 >> 1);
  const int s0 = (w4 & 1) << 4;
  const int base = var_l << 6;
  const int b = bh >> 4, h = bh & 15;

  const bool f32 = detect_f32_spread(Q, blockIdx.x);
  const u16* Kb = Kr + ((size_t)bh << 17);
  const u16* Vb = VT + ((size_t)bh << 17);  // 32 tiles x 4096 elems

  const float LOG2E = 1.4426950408889634f;
  const float bw_diff = f32 ? ((const float*)bw)[h] : bf2f(((const u16*)bw)[h]);
  const float bw_same = f32 ? ((const float*)bw)[H_ + h] : bf2f(((const u16*)bw)[H_ + h]);
  const float C1 = 0.125f * LOG2E;
  const float c2d = bw_diff * LOG2E;
  const float c2s = bw_same * LOG2E;
  const float NEGINF = -__builtin_inff();

  // Q fragments (MFMA B-operand, n=query=l16), RoPE'd in-register.
  bf16x8 qf[2][2];
#pragma unroll
  for (int rh = 0; rh < 2; ++rh) {
    const int r = base + s0 + (rh << 5) + l16;
    size_t ro = (((size_t)(b * L_ + r) * H_ + h) * E_);
    qf[rh][0] = rope_frag(ld8(Q, ro + quad * 8, f32), (float)r, quad);
    qf[rh][1] = ld8(Q, ro + 32 + quad * 8, f32);
  }

  const floatx4 zero4 = {0.f, 0.f, 0.f, 0.f};
  bf16x8 ones;
  { uint4 t4; t4.x = t4.y = t4.z = t4.w = 0x3F803F80u; ones = __builtin_bit_cast(bf16x8, t4); }

  floatx4 oacc[2][4], lacc[2];
#pragma unroll
  for (int rh = 0; rh < 2; ++rh) {
    lacc[rh] = zero4;
#pragma unroll
    for (int c4 = 0; c4 < 4; ++c4) oacc[rh][c4] = zero4;
  }

  // staging: 8 chunks of 1KB per 8KB tile; wave w4 does chunks 2w4,2w4+1 of
  // ITS half's kbuf and vbuf (4 gll16/wave/var).
  const int srow = lane >> 3;          // row-within-chunk 0..7 (= row&7)
  const int sc16 = (lane & 7) ^ srow;  // pre-swizzled global 16B column
#if !HAS_GLL
  uint4 sk[2], sv[2];
#endif
  auto stage_issue = [&](int bufn, int v) {
    const int k0r = v << 6;
#pragma unroll
    for (int rr = 0; rr < 2; ++rr) {
      const int chunk = (w4 << 1) + rr;
      const int row = (chunk << 3) + srow;
      const u16* gk = Kb + (size_t)(k0r + row) * 64 + sc16 * 8;
      const u16* gv = Vb + ((size_t)v << 12) + (size_t)row * 64 + sc16 * 8;
#if HAS_GLL
      gll16(gk, (char*)&kbuf[half][bufn][0][0] + chunk * 1024);
      gll16(gv, (char*)&vbuf[half][bufn][0][0] + chunk * 1024);
#else
      sk[rr] = *(const uint4*)gk;
      sv[rr] = *(const uint4*)gv;
#endif
    }
  };
  auto stage_commit = [&](int bufn) {
#if !HAS_GLL
#pragma unroll
    for (int rr = 0; rr < 2; ++rr) {
      const int chunk = (w4 << 1) + rr;
      *(uint4*)((u16*)&kbuf[half][bufn][0][0] + chunk * 512 + lane * 8) = sk[rr];
      *(uint4*)((u16*)&vbuf[half][bufn][0][0] + chunk * 512 + lane * 8) = sv[rr];
    }
#else
    (void)bufn;
#endif
  };

  const int vbase = half << 4;
  stage_issue(0, vbase);
  stage_commit(0);
  __asm__ volatile("s_waitcnt vmcnt(0)" ::: "memory");
  __syncthreads();

  const int sw = l16 & 7;  // read-side swizzle key (row&7 == l16&7 for all reads)
  u32* const prow = &plds[wid][l16][0];

  // one 32-key tile: softmax + P exchange + rowsum + PV.
  // V fragments loaded HERE (after the fence) so they overlap the MFMAs;
  // vcol selects the key-half of vbuf (0 for kt0, 4 for kt1).
  auto pv_tile = [&](const floatx4 sc[2], bool msk_on, float c2,
                     int rh, int vcol, int buf) {
#pragma unroll
    for (int ch = 0; ch < 2; ++ch) {
      float p[4];
#pragma unroll
      for (int reg = 0; reg < 4; ++reg) {
        const bool msk = msk_on && ((ch * 16 + quad * 4 + reg) > (s0 + l16));
        float s = fmaf(sc[ch][reg], C1, c2);
        if (msk) s = NEGINF;
        p[reg] = exp2_fast(s);
      }
      uint2 w;
      w.x = cvtpk_bf16(p[0], p[1]);
      w.y = cvtpk_bf16(p[2], p[3]);
      *(uint2*)(prow + ch * 8 + quad * 2) = w;  // ds_write_b64
    }
    // COMPILER-ONLY fence: forbids reordering the read above the writes.
    // HW ordering is the per-wave in-order LDS pipe; the read's register
    // dependency gets an automatic counted lgkmcnt from the compiler.
    __asm__ volatile("" ::: "memory");
    bf16x8 pa = __builtin_bit_cast(bf16x8, *(const uint4*)(prow + quad * 4));
    __builtin_amdgcn_s_setprio(1);
    lacc[rh] = __builtin_amdgcn_mfma_f32_16x16x32_bf16(pa, ones, lacc[rh], 0, 0, 0);
#pragma unroll
    for (int c4 = 0; c4 < 4; ++c4) {
      bf16x8 vf = *(const bf16x8*)&vbuf[half][buf][c4 * 16 + l16][((vcol + quad) ^ sw) << 3];
      oacc[rh][c4] = __builtin_amdgcn_mfma_f32_16x16x32_bf16(pa, vf, oacc[rh][c4], 0, 0, 0);
    }
    __builtin_amdgcn_s_setprio(0);
  };

  for (int vi = 0; vi < 16; ++vi) {
    const int v = vbase + vi;
    const int buf = vi & 1;
    const bool more = (vi < 15);
    if (more) stage_issue(buf ^ 1, v + 1);  // prefetch next tile

    const float c2 = (v == var_l) ? c2s : c2d;

    // ---- kt0: load kf, QK for both rh, then kf dies ----
    floatx4 cc[2][2];
    {
      bf16x8 kf[2][2];
#pragma unroll
      for (int ch = 0; ch < 2; ++ch) {
        const int row = ch * 16 + l16;
#pragma unroll
        for (int hf = 0; hf < 2; ++hf)
          kf[ch][hf] = *(const bf16x8*)&kbuf[half][buf][row][(((hf << 2) + quad) ^ sw) << 3];
      }
      __builtin_amdgcn_s_setprio(1);
#pragma unroll
      for (int ch = 0; ch < 2; ++ch)
#pragma unroll
        for (int rh = 0; rh < 2; ++rh) {
          floatx4 a0 = __builtin_amdgcn_mfma_f32_16x16x32_bf16(kf[ch][0], qf[rh][0], zero4, 0, 0, 0);
          cc[rh][ch] = __builtin_amdgcn_mfma_f32_16x16x32_bf16(kf[ch][1], qf[rh][1], a0, 0, 0, 0);
        }
      __builtin_amdgcn_s_setprio(0);
    }
    // ---- kt1: load kg (after kf freed), QK for rh1, kg dies ----
    floatx4 dd[2];
    {
      bf16x8 kg[2][2];
#pragma unroll
      for (int ch = 0; ch < 2; ++ch) {
        const int row = 32 + ch * 16 + l16;
#pragma unroll
        for (int hf = 0; hf < 2; ++hf)
          kg[ch][hf] = *(const bf16x8*)&kbuf[half][buf][row][(((hf << 2) + quad) ^ sw) << 3];
      }
      __builtin_amdgcn_s_setprio(1);
#pragma unroll
      for (int ch = 0; ch < 2; ++ch) {
        floatx4 a1 = __builtin_amdgcn_mfma_f32_16x16x32_bf16(kg[ch][0], qf[1][0], zero4, 0, 0, 0);
        dd[ch] = __builtin_amdgcn_mfma_f32_16x16x32_bf16(kg[ch][1], qf[1][1], a1, 0, 0, 0);
      }
      __builtin_amdgcn_s_setprio(0);
    }

    // three 32-key tiles through the reused per-wave P region:
    pv_tile(cc[0], true, c2, 0, 0, buf);   // rh0 x kt0 (diag-masked)
    pv_tile(cc[1], false, c2, 1, 0, buf);  // rh1 x kt0 (full)
    pv_tile(dd, true, c2, 1, 4, buf);      // rh1 x kt1 (diag-masked)

    if (more) {
      stage_commit(buf ^ 1);
      __asm__ volatile("s_waitcnt vmcnt(0)" ::: "memory");
      __syncthreads();
    }
  }

  // ---- split-K combine: halves' partials simply add (static softmax) ----
  __syncthreads();  // retire last tile's LDS use; kbuf/vbuf space is now free
  float* oscr = (float*)&kbuf[0][0][0][0];  // 32KB = 8192 floats (2 waves/round)
  float* lscr = (float*)&vbuf[0][0][0][0];  // 4KB used
#pragma unroll
  for (int round = 0; round < 2; ++round) {
    const int src0 = 4 + (round << 1);
    if (wid == src0 || wid == src0 + 1) {
      const int slot = wid - src0;
      float* dst = oscr + slot * 4096;
#pragma unroll
      for (int rh = 0; rh < 2; ++rh) {
#pragma unroll
        for (int c4 = 0; c4 < 4; ++c4)
          *(floatx4*)(dst + (rh * 4 + c4) * 256 + lane * 4) = oacc[rh][c4];
        *(floatx4*)(lscr + slot * 512 + lane * 8 + rh * 4) = lacc[rh];
      }
    }
    __syncthreads();
    const int dst0 = round << 1;
    if (wid == dst0 || wid == dst0 + 1) {
      const int slot = wid - dst0;
      const float* src = oscr + slot * 4096;
#pragma unroll
      for (int rh = 0; rh < 2; ++rh) {
#pragma unroll
        for (int c4 = 0; c4 < 4; ++c4)
          oacc[rh][c4] += *(const floatx4*)(src + (rh * 4 + c4) * 256 + lane * 4);
        lacc[rh] += *(const floatx4*)(lscr + slot * 512 + lane * 8 + rh * 4);
      }
    }
    __syncthreads();
  }

  if (half == 0) {
    float rinv[2][4];
#pragma unroll
    for (int rh = 0; rh < 2; ++rh)
#pragma unroll
      for (int reg = 0; reg < 4; ++reg) {
        float lv = lacc[rh][reg];
        rinv[rh][reg] = (lv > 1e-30f) ? 1.0f / lv : 0.0f;
      }
#pragma unroll
    for (int rh = 0; rh < 2; ++rh)
#pragma unroll
      for (int c4 = 0; c4 < 4; ++c4)
#pragma unroll
        for (int reg = 0; reg < 4; ++reg) {
          const int row = base + s0 + (rh << 5) + quad * 4 + reg;
          const int col = c4 * 16 + l16;
          float val = oacc[rh][c4][reg] * rinv[rh][reg];
          size_t oo = (((size_t)(b * L_ + row)) * H_ + h) * E_ + col;
          if (f32) ((float*)out)[oo] = val;
          else ((u16*)out)[oo] = f2bf(val);
        }
  }
}

// ---------- fully-fused fallback (tiny/absent workspace): RoPE + V-transpose in-loop ----------
__global__ __launch_bounds__(256) void flash_fused(
    const void* __restrict__ Q, const void* __restrict__ K,
    const void* __restrict__ V, const void* __restrict__ bw,
    const int* __restrict__ flag, void* __restrict__ out) {
  __shared__ u16 plds[4][2][32 * 36];
  __shared__ u16 vlds[4][64][40];
  const bool f32 = flag ? (*flag != 0) : true;
  const int tid = threadIdx.x;
  const int wid = tid >> 6, lane = tid & 63;
  const int quad = lane >> 4, l16 = lane & 15;
  const int bh = blockIdx.x & 31;
  const int g = blockIdx.x >> 5;
  const int rowblk = (g << 2) + wid;
  const int row0 = rowblk << 5;
  const int b = bh >> 4, h = bh & 15;
  const int t0 = row0 & 63;
  const int var_l = row0 >> 6;
  const int ktiles = (t0 >> 5) + 1;

  const float bw_diff = f32 ? ((const float*)bw)[h] : bf2f(((const u16*)bw)[h]);
  const float bw_same = f32 ? ((const float*)bw)[H_ + h] : bf2f(((const u16*)bw)[H_ + h]);

  const floatx4 zero4 = {0.f, 0.f, 0.f, 0.f};
  bf16x8 ones;
  { uint4 t4; t4.x = t4.y = t4.z = t4.w = 0x3F803F80u; ones = __builtin_bit_cast(bf16x8, t4); }

  bf16x8 qf[2][2];
#pragma unroll
  for (int rh = 0; rh < 2; ++rh) {
    const int r = row0 + rh * 16 + l16;
    size_t ro = (((size_t)(b * L_ + r) * H_ + h) * E_);
#pragma unroll
    for (int hf = 0; hf < 2; ++hf)
      qf[rh][hf] = ld8(Q, ro + hf * 32 + quad * 8, f32);
    qf[rh][0] = rope_frag(qf[rh][0], (float)r, quad);
  }

  floatx4 oacc[2][4], lacc[2];
#pragma unroll
  for (int rh = 0; rh < 2; ++rh) {
    lacc[rh] = zero4;
#pragma unroll
    for (int c4 = 0; c4 < 4; ++c4) oacc[rh][c4] = zero4;
  }

  u16* const pbase = &plds[wid][0][0];
  u16* const vb = &vlds[wid][0][0];
  int pp = 0;

  for (int v = 0; v < 32; ++v) {
    const float bias = (v == var_l) ? bw_same : bw_diff;
    for (int kt = 0; kt < ktiles; ++kt) {
      const int k0 = (v << 6) + (kt << 5);

      bf16x8 kf[2][2];
#pragma unroll
      for (int ch = 0; ch < 2; ++ch) {
        const int r = k0 + ch * 16 + l16;
        size_t ro = (((size_t)(b * L_ + r) * H_ + h) * E_);
#pragma unroll
        for (int hf = 0; hf < 2; ++hf)
          kf[ch][hf] = ld8(K, ro + hf * 32 + quad * 8, f32);
        kf[ch][0] = rope_frag(kf[ch][0], (float)r, quad);
      }

      floatx4 cc[2][2];
#pragma unroll
      for (int rh = 0; rh < 2; ++rh)
#pragma unroll
        for (int ch = 0; ch < 2; ++ch) {
          floatx4 acc = __builtin_amdgcn_mfma_f32_16x16x32_bf16(qf[rh][0], kf[ch][0], zero4, 0, 0, 0);
          cc[rh][ch] = __builtin_amdgcn_mfma_f32_16x16x32_bf16(qf[rh][1], kf[ch][1], acc, 0, 0, 0);
        }

      u16* const pw = pbase + pp * (32 * 36);
      const int ts_b = (kt << 5) + l16;
#pragma unroll
      for (int rh = 0; rh < 2; ++rh)
#pragma unroll
        for (int ch = 0; ch < 2; ++ch) {
          const int ts = ts_b + ch * 16;
#pragma unroll
          for (int reg = 0; reg < 4; ++reg) {
            const int tl = t0 + rh * 16 + quad * 4 + reg;
            float s = cc[rh][ch][reg] * 0.125f + bias;
            float p = (ts > tl) ? 0.0f : __expf(s);
            pw[(rh * 16 + quad * 4 + reg) * 36 + ch * 16 + l16] = f2bf(p);
          }
        }

      // stage V tile (32 keys x 64 dims) transposed into LDS
#pragma unroll
      for (int it = 0; it < 4; ++it) {
        const int s = (lane >> 3) + it * 8;
        const int dc = (lane & 7) << 3;
        size_t vo = (((size_t)(b * L_ + k0 + s) * H_ + h) * E_) + dc;
        bf16x8 x8 = ld8(V, vo, f32);
        uint4 x = __builtin_bit_cast(uint4, x8);
        vb[(dc + 0) * 40 + s] = (u16)x.x; vb[(dc + 1) * 40 + s] = (u16)(x.x >> 16);
        vb[(dc + 2) * 40 + s] = (u16)x.y; vb[(dc + 3) * 40 + s] = (u16)(x.y >> 16);
        vb[(dc + 4) * 40 + s] = (u16)x.z; vb[(dc + 5) * 40 + s] = (u16)(x.z >> 16);
        vb[(dc + 6) * 40 + s] = (u16)x.w; vb[(dc + 7) * 40 + s] = (u16)(x.w >> 16);
      }

      __asm__ volatile("s_waitcnt lgkmcnt(0)" ::: "memory");

      bf16x8 pa[2];
#pragma unroll
      for (int rh = 0; rh < 2; ++rh) {
        const u16* pr = pw + (rh * 16 + l16) * 36 + quad * 8;
        uint2 lo = *(const uint2*)pr;
        uint2 hi = *(const uint2*)(pr + 4);
        uint4 cmb; cmb.x = lo.x; cmb.y = lo.y; cmb.z = hi.x; cmb.w = hi.y;
        pa[rh] = __builtin_bit_cast(bf16x8, cmb);
      }

#pragma unroll
      for (int rh = 0; rh < 2; ++rh)
        lacc[rh] = __builtin_amdgcn_mfma_f32_16x16x32_bf16(pa[rh], ones, lacc[rh], 0, 0, 0);

#pragma unroll
      for (int c4 = 0; c4 < 4; ++c4) {
        bf16x8 vf = *(const bf16x8*)(vb + (c4 * 16 + l16) * 40 + quad * 8);
#pragma unroll
        for (int rh = 0; rh < 2; ++rh)
          oacc[rh][c4] = __builtin_amdgcn_mfma_f32_16x16x32_bf16(pa[rh], vf, oacc[rh][c4], 0, 0, 0);
      }
      pp ^= 1;
    }
  }

  float rinv[2][4];
#pragma unroll
  for (int rh = 0; rh < 2; ++rh)
#pragma unroll
    for (int reg = 0; reg < 4; ++reg) {
      float lv = lacc[rh][reg];
      rinv[rh][reg] = (lv > 1e-30f) ? 1.0f / lv : 0.0f;
    }

#pragma unroll
  for (int rh = 0; rh < 2; ++rh)
#pragma unroll
    for (int c4 = 0; c4 < 4; ++c4)
#pragma unroll
      for (int reg = 0; reg < 4; ++reg) {
        const int row = row0 + rh * 16 + quad * 4 + reg;
        const int col = c4 * 16 + l16;
        float val = oacc[rh][c4][reg] * rinv[rh][reg];
        size_t oo = (((size_t)(b * L_ + row)) * H_ + h) * E_ + col;
        if (f32) ((float*)out)[oo] = val;
        else ((u16*)out)[oo] = f2bf(val);
      }
}

extern "C" void kernel_launch(void* const* d_in, const int* in_sizes, int n_in,
                              void* d_out, int out_size, void* d_ws, size_t ws_size,
                              hipStream_t stream) {
  (void)in_sizes; (void)n_in; (void)out_size;
  const void* q = d_in[0];
  const void* k = d_in[1];
  const void* v = d_in[2];
  const void* bwp = d_in[3];
  // d_in[4]=n_vars(=32), d_in[5]=n_tokens(=64): fixed by setup, hardcoded.
  const size_t need = (size_t)WS_OFF * 2 + 2u * QK_ELEMS * sizeof(u16);  // ~16.8 MB
  if (ws_size >= need) {
    u16* Kr = (u16*)d_ws + WS_OFF;
    u16* VT = Kr + QK_ELEMS;
    prep_kv<<<B_ * L_ / 4 + B_ * H_ * (L_ / 64), 256, 0, stream>>>(q, k, v, Kr, VT);
    flash_v11<<<512, 512, 0, stream>>>(q, Kr, VT, bwp, d_out);
  } else if (ws_size >= sizeof(int)) {
    int* flag = (int*)d_ws;
    detect_dtype<<<1, 64, 0, stream>>>((const u16*)q, flag);
    flash_fused<<<512, 256, 0, stream>>>(q, k, v, bwp, flag, d_out);
  } else {
    flash_fused<<<512, 256, 0, stream>>>(q, k, v, bwp, (const int*)nullptr, d_out);
  }
}